// Round 7
// baseline (662.807 us; speedup 1.0000x reference)
//
#include <hip/hip_runtime.h>

// Problem constants
#define CCH 768
#define NCL 64
#define HWIN 1024                 // 32*32 pixels per batch
#define RES_ELEMS 134217728LL     // 8*64*512*512
#define CODE_ELEMS 6291456LL      // 8*768*32*32
#define CQUADS 1572863LL          // float4 code-copy count
#define ASSIGN_BLOCKS 256
#define COPY_BLOCKS2 512          // copy blocks riding in the assign launch
#define DENSE_BLOCKS 2048         // 8 b * 64 n * 4 chunks of 128 rows

// ---------------------------------------------------------------------------
// Launch B: blocks [0,256): fused cluster-norm + assign, HIGH-OCCUPANCY version.
//   LDS cut 81 KB -> ~17 KB (cg-reduction now intra-wave via shfl_xor), so
//   4 blocks/CU co-reside (vs 1) -> 4x latency hiding on staging + barriers.
//   Thread map: pg = tid&7 (4-px quad), cg = (tid>>3)&7 (96-ch group, LANE
//   bits -> shfl-reducible), ng = tid>>6 (16-n group = wave).
//   Cluster tile staged with column XOR-swizzle col^=(cg(ch)<<2) so the
//   8 cg rows per ds_read_b128 land on 8 distinct bank groups (conflict-free).
// Blocks [256, 768): code-copy into out tail (overlaps with assign compute).
// ---------------------------------------------------------------------------
__global__ __launch_bounds__(256, 4) void k_assign(const float* __restrict__ code,
                                                   const float* __restrict__ clusters,
                                                   int* __restrict__ assign,
                                                   float* __restrict__ loss_part,
                                                   float* __restrict__ out)
{
    int tid = threadIdx.x;
    int blk = blockIdx.x;

    if (blk >= ASSIGN_BLOCKS) {
        // ---- code copy: out[1+RES+e] = code[e], aligned-quad region ----
        long long u = (long long)(blk - ASSIGN_BLOCKS) * 256 + tid;
        #pragma unroll
        for (int k = 0; k < 12; ++k) {
            long long q = u + (long long)k * (COPY_BLOCKS2 * 256);
            if (q < CQUADS) {
                const float* src = code + 3 + 4 * q;          // src misaligned (scalar loads)
                float4 v = make_float4(src[0], src[1], src[2], src[3]);
                *(float4*)(out + RES_ELEMS + 4 + 4 * q) = v;  // dst 16B-aligned
            }
        }
        if (blk == ASSIGN_BLOCKS && tid == 0) {
            out[RES_ELEMS + 1] = code[0];          // code-copy head (3 scalars)
            out[RES_ELEMS + 2] = code[1];
            out[RES_ELEMS + 3] = code[2];
            out[RES_ELEMS + CODE_ELEMS] = code[CODE_ELEMS - 1];   // tail
        }
        return;
    }

    __shared__ float lds_nc[64 * 64];   // 16 KB swizzled cluster tile; reused for dots
    __shared__ float lds_sq[32];        // per-pixel sumsq
    __shared__ float s_scale[64];       // 1/||cluster_n||

    int lane = tid & 63;
    int w = tid >> 6;

    // ---- scale prologue: wave w computes clusters n = w*16 .. w*16+15 ----
    for (int t = 0; t < 16; ++t) {
        int n = w * 16 + t;
        const float* row = clusters + n * CCH;
        float ss = 0.f;
        #pragma unroll
        for (int j = 0; j < 3; ++j) {
            float4 v = *(const float4*)(row + 4 * (lane + 64 * j));
            ss += v.x * v.x + v.y * v.y + v.z * v.z + v.w * v.w;
        }
        #pragma unroll
        for (int m = 1; m < 64; m <<= 1) ss += __shfl_xor(ss, m);
        if (lane == 0) s_scale[n] = 1.0f / fmaxf(sqrtf(ss), 1e-12f);
    }
    __syncthreads();

    int pg = tid & 7;          // pixel quad (lane bits 0-2)
    int cg = (tid >> 3) & 7;   // channel group (lane bits 3-5) -> shfl-reducible
    int ng = tid >> 6;         // cluster group = wave id
    int b = blk >> 5;
    int pixb = (blk & 31) << 5;
    const float* codeB = code + (size_t)b * CCH * HWIN + pixb + (pg << 2);

    // staging role: thread stages cluster n2, quarter qq (16 channels)
    int n2 = tid >> 2;
    int qq = tid & 3;
    float myscale = s_scale[n2];

    float acc[4][16];
    #pragma unroll
    for (int p = 0; p < 4; ++p)
        #pragma unroll
        for (int q = 0; q < 16; ++q) acc[p][q] = 0.f;
    float sq0 = 0.f, sq1 = 0.f, sq2 = 0.f, sq3 = 0.f;

    for (int k = 0; k < 12; ++k) {
        __syncthreads();
        // stage transposed+scaled+SWIZZLED tile:
        //   lds_nc[ch][ n ^ ((ch>>3)<<2) ] = clusters[n][k*64+ch] * scale[n]
        const float* srcrow = clusters + n2 * CCH + k * 64 + qq * 16;
        #pragma unroll
        for (int i = 0; i < 4; ++i) {
            float4 v = *(const float4*)(srcrow + 4 * i);
            int c0 = qq * 16 + 4 * i;
            lds_nc[(c0 + 0) * 64 + (n2 ^ (((c0 + 0) >> 3) << 2))] = v.x * myscale;
            lds_nc[(c0 + 1) * 64 + (n2 ^ (((c0 + 1) >> 3) << 2))] = v.y * myscale;
            lds_nc[(c0 + 2) * 64 + (n2 ^ (((c0 + 2) >> 3) << 2))] = v.z * myscale;
            lds_nc[(c0 + 3) * 64 + (n2 ^ (((c0 + 3) >> 3) << 2))] = v.w * myscale;
        }
        __syncthreads();
        #pragma unroll
        for (int m = 0; m < 8; ++m) {
            int chl = cg * 8 + m;
            float4 f = *(const float4*)(codeB + (size_t)(k * 64 + chl) * HWIN);
            sq0 += f.x * f.x; sq1 += f.y * f.y; sq2 += f.z * f.z; sq3 += f.w * f.w;
            const float* basep = lds_nc + (chl << 6);
            #pragma unroll
            for (int u = 0; u < 4; ++u) {
                float4 wv = *(const float4*)(basep + (((ng * 16 + 4 * u) ^ (cg << 2))));
                float wl[4] = { wv.x, wv.y, wv.z, wv.w };
                #pragma unroll
                for (int v2 = 0; v2 < 4; ++v2) {
                    float w2 = wl[v2];
                    int q = 4 * u + v2;
                    acc[0][q] += f.x * w2;
                    acc[1][q] += f.y * w2;
                    acc[2][q] += f.z * w2;
                    acc[3][q] += f.w * w2;
                }
            }
        }
    }

    // ---- reduce over cg (lane bits 3-5) via 3 shfl_xor rounds ----
    #pragma unroll
    for (int mask = 8; mask <= 32; mask <<= 1) {
        #pragma unroll
        for (int p = 0; p < 4; ++p)
            #pragma unroll
            for (int q = 0; q < 16; ++q)
                acc[p][q] += __shfl_xor(acc[p][q], mask);
        sq0 += __shfl_xor(sq0, mask);
        sq1 += __shfl_xor(sq1, mask);
        sq2 += __shfl_xor(sq2, mask);
        sq3 += __shfl_xor(sq3, mask);
    }

    __syncthreads();   // all main-loop lds_nc reads complete before overwrite

    if (cg == 0) {
        #pragma unroll
        for (int p = 0; p < 4; ++p) {
            float* d = &lds_nc[(pg * 4 + p) * 64 + ng * 16];
            *(float4*)(d + 0)  = make_float4(acc[p][0],  acc[p][1],  acc[p][2],  acc[p][3]);
            *(float4*)(d + 4)  = make_float4(acc[p][4],  acc[p][5],  acc[p][6],  acc[p][7]);
            *(float4*)(d + 8)  = make_float4(acc[p][8],  acc[p][9],  acc[p][10], acc[p][11]);
            *(float4*)(d + 12) = make_float4(acc[p][12], acc[p][13], acc[p][14], acc[p][15]);
        }
        if (ng == 0) {
            lds_sq[pg * 4 + 0] = sq0;
            lds_sq[pg * 4 + 1] = sq1;
            lds_sq[pg * 4 + 2] = sq2;
            lds_sq[pg * 4 + 3] = sq3;
        }
    }
    __syncthreads();

    if (tid < 32) {
        float ss = lds_sq[tid];
        float inv = 1.0f / fmaxf(sqrtf(ss), 1e-12f);
        float best = -1e30f; int bi = 0;
        for (int n = 0; n < 64; ++n) {
            float v = lds_nc[tid * 64 + n];   // already scaled by 1/||cluster||
            if (v > best) { best = v; bi = n; }
        }
        assign[blk * 32 + tid] = bi;
        float l = best * inv;
        l += __shfl_down(l, 16);
        l += __shfl_down(l, 8);
        l += __shfl_down(l, 4);
        l += __shfl_down(l, 2);
        l += __shfl_down(l, 1);
        if (tid == 0) loss_part[blk] = -l * (1.0f / 8192.0f);
    }
}

// ---------------------------------------------------------------------------
// Launch C: k_dense: 2048 blocks: block = (b, n, 128-row chunk) writes a
// CONTIGUOUS 256 KB chunk of one plane. One-hot via per-input-row 32-bit
// bitmasks (ballot). Block 0 additionally reduces the 256 loss partials.
// ---------------------------------------------------------------------------
__global__ __launch_bounds__(256) void k_dense(const int* __restrict__ assign,
                                               const float* __restrict__ loss_part,
                                               float* __restrict__ out)
{
    int tid = threadIdx.x;
    int blk = blockIdx.x;

    if (blk == 0) {
        __shared__ float lr[4];
        float v = loss_part[tid];
        #pragma unroll
        for (int m = 1; m < 64; m <<= 1) v += __shfl_xor(v, m);
        if ((tid & 63) == 0) lr[tid >> 6] = v;
        __syncthreads();
        if (tid == 0) out[0] = lr[0] + lr[1] + lr[2] + lr[3];
    }

    int b =  blk >> 8;          // batch 0..7
    int n = (blk >> 2) & 63;    // plane 0..63
    int c =  blk & 3;           // row-chunk 0..3
    int I0 = c << 7;            // first output row of chunk (128 rows)
    int rbase = (I0 >> 4) - 1;  // first (unclamped) input row referenced

    __shared__ unsigned s_mask[10];   // per-input-row one-hot bitmaps for n
    __shared__ int4   s_jj[128];      // packed j0|j1<<8 per j of slot
    __shared__ float4 s_fj[128];      // fj per j of slot

    int lane = tid & 63;
    int w = tid >> 6;

    // ---- bitmask build: rows 0..7 by waves 0..3; rows 8..9 by wave 0 ----
    {
        int r = (w << 1) + (lane >> 5);
        int ir = rbase + r; ir = ir < 0 ? 0 : (ir > 31 ? 31 : ir);
        bool pred = assign[(b << 10) + (ir << 5) + (lane & 31)] == n;
        unsigned long long m = __ballot(pred);
        if (lane == 0) { s_mask[(w << 1)] = (unsigned)m; s_mask[(w << 1) + 1] = (unsigned)(m >> 32); }
    }
    if (w == 0) {
        int r = 8 + (lane >> 5);
        int ir = rbase + r; ir = ir < 0 ? 0 : (ir > 31 ? 31 : ir);
        bool pred = assign[(b << 10) + (ir << 5) + (lane & 31)] == n;
        unsigned long long m = __ballot(pred);
        if (lane == 0) { s_mask[8] = (unsigned)m; s_mask[9] = (unsigned)(m >> 32); }
    }

    // ---- per-slot j tables ----
    if (tid < 128) {
        int s = tid;
        int jl[4];
        if (s == 0) { jl[0] = 0; jl[1] = 1; jl[2] = 2; jl[3] = 511; }
        else { jl[0] = 4 * s - 1; jl[1] = 4 * s; jl[2] = 4 * s + 1; jl[3] = 4 * s + 2; }
        int pj[4]; float fjv[4];
        #pragma unroll
        for (int k = 0; k < 4; ++k) {
            int j = jl[k];
            float xj = (j + 0.5f) * 0.0625f - 0.5f;
            float fjf = floorf(xj);
            int jj = (int)fjf;
            fjv[k] = xj - fjf;
            int j0 = jj < 0 ? 0 : jj;
            int j1 = (jj + 1) > 31 ? 31 : (jj + 1);
            pj[k] = j0 | (j1 << 8);
        }
        s_jj[s] = make_int4(pj[0], pj[1], pj[2], pj[3]);
        s_fj[s] = make_float4(fjv[0], fjv[1], fjv[2], fjv[3]);
    }
    __syncthreads();

    int rr = tid >> 7;          // which of the 2 rows per iteration
    int s  = tid & 127;         // column slot
    int4   pj4 = s_jj[s];       // hoisted per-thread constants
    float4 fj4 = s_fj[s];
    int   j0a[4] = { pj4.x & 255, pj4.y & 255, pj4.z & 255, pj4.w & 255 };
    int   j1a[4] = { pj4.x >> 8,  pj4.y >> 8,  pj4.z >> 8,  pj4.w >> 8 };
    float fja[4] = { fj4.x, fj4.y, fj4.z, fj4.w };

    long long planebase = 1LL + ((long long)b << 24) + ((long long)n << 18);

    for (int r2 = 0; r2 < 64; ++r2) {
        int i = I0 + (r2 << 1) + rr;
        float xi = (i + 0.5f) * 0.0625f - 0.5f;
        float fif = floorf(xi);
        int ii = (int)fif;
        float fi = xi - fif;
        float fi1 = 1.0f - fi;
        unsigned m0 = s_mask[ii - rbase];        // uniform across row's threads
        unsigned m1 = s_mask[ii - rbase + 1];
        float v[4];
        #pragma unroll
        for (int k = 0; k < 4; ++k) {
            float b00 = (float)((m0 >> j0a[k]) & 1u);
            float b01 = (float)((m0 >> j1a[k]) & 1u);
            float b10 = (float)((m1 >> j0a[k]) & 1u);
            float b11 = (float)((m1 >> j1a[k]) & 1u);
            float P = fi1 * b00 + fi * b10;
            float Q = fi1 * b01 + fi * b11;
            v[k] = P + fja[k] * (Q - P);
        }
        float* rowbase = out + planebase + ((long long)i << 9);
        if (s == 0) {
            rowbase[0] = v[0]; rowbase[1] = v[1]; rowbase[2] = v[2]; rowbase[511] = v[3];
        } else {
            *(float4*)(rowbase + 4 * s - 1) = make_float4(v[0], v[1], v[2], v[3]);
        }
    }
}

// ---------------------------------------------------------------------------
extern "C" void kernel_launch(void* const* d_in, const int* in_sizes, int n_in,
                              void* d_out, int out_size, void* d_ws, size_t ws_size,
                              hipStream_t stream)
{
    const float* code     = (const float*)d_in[0];   // [8,768,32,32]
    const float* clusters = (const float*)d_in[1];   // [64,768]
    float* out = (float*)d_out;                      // [loss | resized | code]
    int* assign = (int*)d_ws;                        // 8192 ints
    float* loss_part = (float*)((char*)d_ws + 32768); // 256 floats

    k_assign<<<ASSIGN_BLOCKS + COPY_BLOCKS2, 256, 0, stream>>>(code, clusters, assign, loss_part, out);
    k_dense <<<DENSE_BLOCKS,                 256, 0, stream>>>(assign, loss_part, out);
}

// Round 8
// 611.897 us; speedup vs baseline: 1.0832x; 1.0832x over previous
//
#include <hip/hip_runtime.h>

// Problem constants
#define CCH 768
#define NCL 64
#define HWIN 1024                 // 32*32 pixels per batch
#define RES_ELEMS 134217728LL     // 8*64*512*512
#define CODE_ELEMS 6291456LL      // 8*768*32*32
#define CQUADS 1572863LL          // float4 code-copy count
#define ASSIGN_BLOCKS 256
#define COPY_BLOCKS2 512          // copy blocks riding in the assign launch
#define DENSE_BLOCKS 2048         // 8 b * 64 n * 4 chunks of 128 rows

// ---------------------------------------------------------------------------
// Launch B: blocks [0,256): fused cluster-norm + assign (R6 structure, 3 blk/CU).
//   After the acc loop, ONE shfl_xor(32) round folds cg-pairs (cg bit0 = lane
//   bit 5), so only 4 cg-groups dump partials -> lds_red 64KB -> 32KB.
//   Total LDS ~48.8KB -> 3 blocks/CU (vs 1) for 3x latency hiding.
//   No __launch_bounds__ min-waves (R7's 128-VGPR cap suspected spill cause).
// Blocks [256, 768): code-copy into out tail (overlaps with assign compute).
// ---------------------------------------------------------------------------
__global__ __launch_bounds__(256) void k_assign(const float* __restrict__ code,
                                                const float* __restrict__ clusters,
                                                int* __restrict__ assign,
                                                float* __restrict__ loss_part,
                                                float* __restrict__ out)
{
    int tid = threadIdx.x;
    int blk = blockIdx.x;

    if (blk >= ASSIGN_BLOCKS) {
        // ---- code copy: out[1+RES+e] = code[e], aligned-quad region ----
        long long u = (long long)(blk - ASSIGN_BLOCKS) * 256 + tid;
        #pragma unroll
        for (int k = 0; k < 12; ++k) {
            long long q = u + (long long)k * (COPY_BLOCKS2 * 256);
            if (q < CQUADS) {
                const float* src = code + 3 + 4 * q;          // src misaligned (scalar loads)
                float4 v = make_float4(src[0], src[1], src[2], src[3]);
                *(float4*)(out + RES_ELEMS + 4 + 4 * q) = v;  // dst 16B-aligned
            }
        }
        if (blk == ASSIGN_BLOCKS && tid == 0) {
            out[RES_ELEMS + 1] = code[0];          // code-copy head (3 scalars)
            out[RES_ELEMS + 2] = code[1];
            out[RES_ELEMS + 3] = code[2];
            out[RES_ELEMS + CODE_ELEMS] = code[CODE_ELEMS - 1];   // tail
        }
        return;
    }

    __shared__ float lds_nc[64 * 64];     // 16 KB staging; reused for reduced dots
    __shared__ float lds_red[4 * 2048];   // 32 KB cg-pair partials (was 64 KB)
    __shared__ float lds_sq[4 * 32];      // sumsq partials
    __shared__ float s_scale[64];         // 1/||cluster_n||

    int lane = tid & 63;
    int w = tid >> 6;

    // ---- scale prologue: wave w computes clusters n = w*16 .. w*16+15 ----
    for (int t = 0; t < 16; ++t) {
        int n = w * 16 + t;
        const float* row = clusters + n * CCH;
        float ss = 0.f;
        #pragma unroll
        for (int j = 0; j < 3; ++j) {
            float4 v = *(const float4*)(row + 4 * (lane + 64 * j));
            ss += v.x * v.x + v.y * v.y + v.z * v.z + v.w * v.w;
        }
        #pragma unroll
        for (int m = 1; m < 64; m <<= 1) ss += __shfl_xor(ss, m);
        if (lane == 0) s_scale[n] = 1.0f / fmaxf(sqrtf(ss), 1e-12f);
    }
    __syncthreads();

    int cg = tid >> 5;          // channel group 0..7 (bit0 of cg = lane bit 5)
    int ng = (tid >> 3) & 3;
    int pg = tid & 7;
    int b = blk >> 5;
    int pixb = (blk & 31) << 5;
    const float* codeB = code + (size_t)b * CCH * HWIN + pixb + (pg << 2);

    // staging role: this thread stages cluster n2, quarter qq (16 channels)
    int n2 = tid >> 2;
    int qq = tid & 3;
    float myscale = s_scale[n2];

    float acc[4][16];
    #pragma unroll
    for (int p = 0; p < 4; ++p)
        #pragma unroll
        for (int q = 0; q < 16; ++q) acc[p][q] = 0.f;
    float sq0 = 0.f, sq1 = 0.f, sq2 = 0.f, sq3 = 0.f;

    for (int k = 0; k < 12; ++k) {
        __syncthreads();
        // stage transposed+scaled tile: lds_nc[cc][n] = clusters[n][k*64+cc]*scale[n]
        const float* srcrow = clusters + n2 * CCH + k * 64 + qq * 16;
        #pragma unroll
        for (int i = 0; i < 4; ++i) {
            float4 v = *(const float4*)(srcrow + 4 * i);
            lds_nc[(qq * 16 + 4 * i + 0) * 64 + n2] = v.x * myscale;
            lds_nc[(qq * 16 + 4 * i + 1) * 64 + n2] = v.y * myscale;
            lds_nc[(qq * 16 + 4 * i + 2) * 64 + n2] = v.z * myscale;
            lds_nc[(qq * 16 + 4 * i + 3) * 64 + n2] = v.w * myscale;
        }
        __syncthreads();
        #pragma unroll
        for (int m = 0; m < 8; ++m) {
            int ch = k * 64 + cg * 8 + m;
            float4 f = *(const float4*)(codeB + (size_t)ch * HWIN);
            sq0 += f.x * f.x; sq1 += f.y * f.y; sq2 += f.z * f.z; sq3 += f.w * f.w;
            const float* ncrow = lds_nc + ((cg * 8 + m) << 6) + (ng << 4);
            #pragma unroll
            for (int q = 0; q < 16; ++q) {
                float w2 = ncrow[q];
                acc[0][q] += f.x * w2;
                acc[1][q] += f.y * w2;
                acc[2][q] += f.z * w2;
                acc[3][q] += f.w * w2;
            }
        }
    }

    // ---- fold cg-pairs (2j, 2j+1) with one shfl round over lane bit 5 ----
    #pragma unroll
    for (int p = 0; p < 4; ++p)
        #pragma unroll
        for (int q = 0; q < 16; ++q)
            acc[p][q] += __shfl_xor(acc[p][q], 32);
    sq0 += __shfl_xor(sq0, 32);
    sq1 += __shfl_xor(sq1, 32);
    sq2 += __shfl_xor(sq2, 32);
    sq3 += __shfl_xor(sq3, 32);

    if ((tid & 32) == 0) {       // surviving half-wave: group w = tid>>6 (0..3)
        #pragma unroll
        for (int p = 0; p < 4; ++p) {
            float4* dstp = (float4*)&lds_red[w * 2048 + (pg * 4 + p) * 64 + ng * 16];
            dstp[0] = make_float4(acc[p][0],  acc[p][1],  acc[p][2],  acc[p][3]);
            dstp[1] = make_float4(acc[p][4],  acc[p][5],  acc[p][6],  acc[p][7]);
            dstp[2] = make_float4(acc[p][8],  acc[p][9],  acc[p][10], acc[p][11]);
            dstp[3] = make_float4(acc[p][12], acc[p][13], acc[p][14], acc[p][15]);
        }
        if (ng == 0) {
            lds_sq[w * 32 + pg * 4 + 0] = sq0;
            lds_sq[w * 32 + pg * 4 + 1] = sq1;
            lds_sq[w * 32 + pg * 4 + 2] = sq2;
            lds_sq[w * 32 + pg * 4 + 3] = sq3;
        }
    }
    __syncthreads();

    for (int idx = tid; idx < 2048; idx += 256) {
        float s = 0.f;
        #pragma unroll
        for (int c2 = 0; c2 < 4; ++c2) s += lds_red[c2 * 2048 + idx];
        lds_nc[idx] = s;
    }
    __syncthreads();

    if (tid < 32) {
        float ss = 0.f;
        #pragma unroll
        for (int c2 = 0; c2 < 4; ++c2) ss += lds_sq[c2 * 32 + tid];
        float inv = 1.0f / fmaxf(sqrtf(ss), 1e-12f);
        float best = -1e30f; int bi = 0;
        for (int n = 0; n < 64; ++n) {
            float v = lds_nc[tid * 64 + n];   // already scaled by 1/||cluster||
            if (v > best) { best = v; bi = n; }
        }
        assign[blk * 32 + tid] = bi;
        float l = best * inv;
        l += __shfl_down(l, 16);
        l += __shfl_down(l, 8);
        l += __shfl_down(l, 4);
        l += __shfl_down(l, 2);
        l += __shfl_down(l, 1);
        if (tid == 0) loss_part[blk] = -l * (1.0f / 8192.0f);
    }
}

// ---------------------------------------------------------------------------
// Launch C: k_dense: 2048 blocks: block = (b, n, 128-row chunk) writes a
// CONTIGUOUS 256 KB chunk of one plane. One-hot via per-input-row 32-bit
// bitmasks (ballot). Block 0 additionally reduces the 256 loss partials.
// ---------------------------------------------------------------------------
__global__ __launch_bounds__(256) void k_dense(const int* __restrict__ assign,
                                               const float* __restrict__ loss_part,
                                               float* __restrict__ out)
{
    int tid = threadIdx.x;
    int blk = blockIdx.x;

    if (blk == 0) {
        __shared__ float lr[4];
        float v = loss_part[tid];
        #pragma unroll
        for (int m = 1; m < 64; m <<= 1) v += __shfl_xor(v, m);
        if ((tid & 63) == 0) lr[tid >> 6] = v;
        __syncthreads();
        if (tid == 0) out[0] = lr[0] + lr[1] + lr[2] + lr[3];
    }

    int b =  blk >> 8;          // batch 0..7
    int n = (blk >> 2) & 63;    // plane 0..63
    int c =  blk & 3;           // row-chunk 0..3
    int I0 = c << 7;            // first output row of chunk (128 rows)
    int rbase = (I0 >> 4) - 1;  // first (unclamped) input row referenced

    __shared__ unsigned s_mask[10];   // per-input-row one-hot bitmaps for n
    __shared__ int4   s_jj[128];      // packed j0|j1<<8 per j of slot
    __shared__ float4 s_fj[128];      // fj per j of slot

    int lane = tid & 63;
    int w = tid >> 6;

    // ---- bitmask build: rows 0..7 by waves 0..3; rows 8..9 by wave 0 ----
    {
        int r = (w << 1) + (lane >> 5);
        int ir = rbase + r; ir = ir < 0 ? 0 : (ir > 31 ? 31 : ir);
        bool pred = assign[(b << 10) + (ir << 5) + (lane & 31)] == n;
        unsigned long long m = __ballot(pred);
        if (lane == 0) { s_mask[(w << 1)] = (unsigned)m; s_mask[(w << 1) + 1] = (unsigned)(m >> 32); }
    }
    if (w == 0) {
        int r = 8 + (lane >> 5);
        int ir = rbase + r; ir = ir < 0 ? 0 : (ir > 31 ? 31 : ir);
        bool pred = assign[(b << 10) + (ir << 5) + (lane & 31)] == n;
        unsigned long long m = __ballot(pred);
        if (lane == 0) { s_mask[8] = (unsigned)m; s_mask[9] = (unsigned)(m >> 32); }
    }

    // ---- per-slot j tables ----
    if (tid < 128) {
        int s = tid;
        int jl[4];
        if (s == 0) { jl[0] = 0; jl[1] = 1; jl[2] = 2; jl[3] = 511; }
        else { jl[0] = 4 * s - 1; jl[1] = 4 * s; jl[2] = 4 * s + 1; jl[3] = 4 * s + 2; }
        int pj[4]; float fjv[4];
        #pragma unroll
        for (int k = 0; k < 4; ++k) {
            int j = jl[k];
            float xj = (j + 0.5f) * 0.0625f - 0.5f;
            float fjf = floorf(xj);
            int jj = (int)fjf;
            fjv[k] = xj - fjf;
            int j0 = jj < 0 ? 0 : jj;
            int j1 = (jj + 1) > 31 ? 31 : (jj + 1);
            pj[k] = j0 | (j1 << 8);
        }
        s_jj[s] = make_int4(pj[0], pj[1], pj[2], pj[3]);
        s_fj[s] = make_float4(fjv[0], fjv[1], fjv[2], fjv[3]);
    }
    __syncthreads();

    int rr = tid >> 7;          // which of the 2 rows per iteration
    int s  = tid & 127;         // column slot
    int4   pj4 = s_jj[s];       // hoisted per-thread constants
    float4 fj4 = s_fj[s];
    int   j0a[4] = { pj4.x & 255, pj4.y & 255, pj4.z & 255, pj4.w & 255 };
    int   j1a[4] = { pj4.x >> 8,  pj4.y >> 8,  pj4.z >> 8,  pj4.w >> 8 };
    float fja[4] = { fj4.x, fj4.y, fj4.z, fj4.w };

    long long planebase = 1LL + ((long long)b << 24) + ((long long)n << 18);

    for (int r2 = 0; r2 < 64; ++r2) {
        int i = I0 + (r2 << 1) + rr;
        float xi = (i + 0.5f) * 0.0625f - 0.5f;
        float fif = floorf(xi);
        int ii = (int)fif;
        float fi = xi - fif;
        float fi1 = 1.0f - fi;
        unsigned m0 = s_mask[ii - rbase];        // uniform across row's threads
        unsigned m1 = s_mask[ii - rbase + 1];
        float v[4];
        #pragma unroll
        for (int k = 0; k < 4; ++k) {
            float b00 = (float)((m0 >> j0a[k]) & 1u);
            float b01 = (float)((m0 >> j1a[k]) & 1u);
            float b10 = (float)((m1 >> j0a[k]) & 1u);
            float b11 = (float)((m1 >> j1a[k]) & 1u);
            float P = fi1 * b00 + fi * b10;
            float Q = fi1 * b01 + fi * b11;
            v[k] = P + fja[k] * (Q - P);
        }
        float* rowbase = out + planebase + ((long long)i << 9);
        if (s == 0) {
            rowbase[0] = v[0]; rowbase[1] = v[1]; rowbase[2] = v[2]; rowbase[511] = v[3];
        } else {
            *(float4*)(rowbase + 4 * s - 1) = make_float4(v[0], v[1], v[2], v[3]);
        }
    }
}

// ---------------------------------------------------------------------------
extern "C" void kernel_launch(void* const* d_in, const int* in_sizes, int n_in,
                              void* d_out, int out_size, void* d_ws, size_t ws_size,
                              hipStream_t stream)
{
    const float* code     = (const float*)d_in[0];   // [8,768,32,32]
    const float* clusters = (const float*)d_in[1];   // [64,768]
    float* out = (float*)d_out;                      // [loss | resized | code]
    int* assign = (int*)d_ws;                        // 8192 ints
    float* loss_part = (float*)((char*)d_ws + 32768); // 256 floats

    k_assign<<<ASSIGN_BLOCKS + COPY_BLOCKS2, 256, 0, stream>>>(code, clusters, assign, loss_part, out);
    k_dense <<<DENSE_BLOCKS,                 256, 0, stream>>>(assign, loss_part, out);
}